// Round 6
// baseline (1106.731 us; speedup 1.0000x reference)
//
#include <hip/hip_runtime.h>
#include <cstdint>
#include <cstddef>

// Problem constants (fixed by reference)
#define BDIM 8
#define NSEQ 8192
#define CDIM 512
#define HEADS 8
#define HD 64
#define NSPLIT 16

typedef short bf16x8 __attribute__((ext_vector_type(8)));
typedef float f32x4 __attribute__((ext_vector_type(4)));

typedef const __attribute__((address_space(1))) void* gas_cvp;
typedef __attribute__((address_space(3))) void* las_vp;

// Async 16B global->LDS. LDS dest is wave-uniform base + lane*16 (HW adds it).
__device__ __forceinline__ void gload_lds16(const void* g, void* l) {
    __builtin_amdgcn_global_load_lds((gas_cvp)g, (las_vp)l, 16, 0, 0);
}

// bf16 helpers
__device__ __forceinline__ ushort f2bf_rne(float f) {
    uint32_t u = __float_as_uint(f);
    u += 0x7FFFu + ((u >> 16) & 1u);
    return (ushort)(u >> 16);
}
__device__ __forceinline__ float bf2f(ushort h) {
    return __uint_as_float(((uint32_t)h) << 16);
}

// Truncation-based hi/lo split of 8 fp32 -> bf16x8 hi, bf16x8 lo.
// hi = trunc16(x); r = x - hi (EXACT in fp32); lo = trunc16(r).
// Dropped al*bl term in the 3-product GEMM ~2^-16 rel.
__device__ __forceinline__ void split8(const float4 p0, const float4 p1,
                                       bf16x8& hi, bf16x8& lo) {
    const float xs[8] = {p0.x, p0.y, p0.z, p0.w, p1.x, p1.y, p1.z, p1.w};
#pragma unroll
    for (int e = 0; e < 8; ++e) {
        const uint32_t u = __float_as_uint(xs[e]);
        const ushort h = (ushort)(u >> 16);
        const float r = xs[e] - __uint_as_float((uint32_t)h << 16);
        hi[e] = (short)h;
        lo[e] = (short)(__float_as_uint(r) >> 16);
    }
}

// elu(x)+1 with alpha=1:  x>0 ? x+1 : exp(x)
__device__ __forceinline__ float elu1(float x) {
    return x > 0.f ? x + 1.f : __expf(x);
}

// ---------------------------------------------------------------------------
// Pre-pass: W [512][N] f32 -> WT_hi/WT_lo [N][512] bf16 (transpose + split, RNE)
// grid (N/32, 16), block 256 (32x8)
// ---------------------------------------------------------------------------
__global__ __launch_bounds__(256)
void split_wT_kernel(const float* __restrict__ W, ushort* __restrict__ WTh,
                     ushort* __restrict__ WTl, int N) {
    __shared__ float tile[32][33];
    const int tx = threadIdx.x & 31, ty = threadIdx.x >> 5;
    const int bx = blockIdx.x, by = blockIdx.y;
#pragma unroll
    for (int r = 0; r < 4; ++r)
        tile[ty + 8 * r][tx] = W[(size_t)(by * 32 + ty + 8 * r) * N + bx * 32 + tx];
    __syncthreads();
#pragma unroll
    for (int r = 0; r < 4; ++r) {
        const int n = bx * 32 + ty + 8 * r;   // output row (N-dim)
        const int k = by * 32 + tx;           // output col (K-dim)
        const float v = tile[tx][ty + 8 * r]; // = W[k][n]
        const ushort h = f2bf_rne(v);
        WTh[(size_t)n * 512 + k] = h;
        WTl[(size_t)n * 512 + k] = f2bf_rne(v - bf2f(h));
    }
}

// ---------------------------------------------------------------------------
// GEMM 1: qkv = x @ w_qkv (M=65536, N=1536, K=512) with fp32 A read DIRECTLY
// into register fragments + in-register hi/lo split; B (weights, pre-split)
// staged in LDS via fragment-gather global_load_lds.  128x128 tile, BK=32,
// 4 waves (2x2).  Epilogue: elu+1 on q,k; scatter to [B,H,N,D] fp32.
// grid 6144 linear (XCD-swizzled), block 256.
// mfma_f32_16x16x32_bf16 lane layouts: A row=l&15, k=(l>>4)*8+e; B col=l&15,
// k=(l>>4)*8+e; D col=l&15, row=(l>>4)*4+reg.
// ---------------------------------------------------------------------------
__global__ __launch_bounds__(256, 2)
void qkv_mfma_kernel(const float* __restrict__ X,
                     const ushort* __restrict__ BTh, const ushort* __restrict__ BTl,
                     float* __restrict__ qf, float* __restrict__ kf, float* __restrict__ v) {
    // LDS: [buf 2][arr {Bh,Bl}][frag 8][64 lanes * 16B] = 32 KB
    __shared__ __align__(16) char lds[32768];
    const int t = threadIdx.x, l = t & 63, w = t >> 6;
    const int wm = w >> 1, wn = w & 1;
    const int bid = blockIdx.x;
    const int swz = (bid & 7) * 768 + (bid >> 3);  // bijective: 6144 % 8 == 0
    const int brow = swz / 12, bcol = swz % 12;

    // B fragment-gather bases: wave w stages frags {2w, 2w+1} of Bh and Bl
    const int f0 = 2 * w, f1 = 2 * w + 1;
    const ushort* gb0 = BTh + (size_t)(bcol * 128 + f0 * 16 + (l & 15)) * 512 + ((l >> 4) * 8);
    const ushort* gb1 = BTh + (size_t)(bcol * 128 + f1 * 16 + (l & 15)) * 512 + ((l >> 4) * 8);
    const ushort* gb2 = BTl + (size_t)(bcol * 128 + f0 * 16 + (l & 15)) * 512 + ((l >> 4) * 8);
    const ushort* gb3 = BTl + (size_t)(bcol * 128 + f1 * 16 + (l & 15)) * 512 + ((l >> 4) * 8);

    // A fragment base (fp32 direct-to-reg): frag i row = brow*128+wm*64+i*16+(l&15)
    const float* gA = X + (size_t)(brow * 128 + wm * 64 + (l & 15)) * 512 + ((l >> 4) * 8);

    f32x4 acc[4][4];
    const f32x4 zero = {0.f, 0.f, 0.f, 0.f};
#pragma unroll
    for (int i = 0; i < 4; ++i)
#pragma unroll
        for (int j = 0; j < 4; ++j) acc[i][j] = zero;

    auto stage = [&](int buf, int kt) {
        char* Ld = lds + buf * 16384;
        gload_lds16(gb0 + kt, Ld + 0 * 8192 + f0 * 1024);
        gload_lds16(gb1 + kt, Ld + 0 * 8192 + f1 * 1024);
        gload_lds16(gb2 + kt, Ld + 1 * 8192 + f0 * 1024);
        gload_lds16(gb3 + kt, Ld + 1 * 8192 + f1 * 1024);
    };

    stage(0, 0);
    __syncthreads();   // drains vmcnt(0): buffer 0 ready
    int cur = 0;
    for (int ks = 0; ks < 16; ++ks) {
        const int kt = ks * 32;
        if (ks < 15) stage(cur ^ 1, kt + 32);
        // A: fp32 direct loads + in-register split (x is L3-resident, 12x reuse)
        bf16x8 ah[4], al[4];
#pragma unroll
        for (int i = 0; i < 4; ++i) {
            const float* pa = gA + (size_t)i * 16 * 512 + kt;
            const float4 p0 = *(const float4*)(pa);
            const float4 p1 = *(const float4*)(pa + 4);
            split8(p0, p1, ah[i], al[i]);
        }
        const char* Lb = lds + cur * 16384;
        bf16x8 bh[4], bl[4];
#pragma unroll
        for (int j = 0; j < 4; ++j) {
            bh[j] = *(const bf16x8*)(Lb + 0 * 8192 + (wn * 4 + j) * 1024 + l * 16);
            bl[j] = *(const bf16x8*)(Lb + 1 * 8192 + (wn * 4 + j) * 1024 + l * 16);
        }
#pragma unroll
        for (int i = 0; i < 4; ++i)
#pragma unroll
            for (int j = 0; j < 4; ++j) {
                acc[i][j] = __builtin_amdgcn_mfma_f32_16x16x32_bf16(ah[i], bh[j], acc[i][j], 0, 0, 0);
                acc[i][j] = __builtin_amdgcn_mfma_f32_16x16x32_bf16(ah[i], bl[j], acc[i][j], 0, 0, 0);
                acc[i][j] = __builtin_amdgcn_mfma_f32_16x16x32_bf16(al[i], bh[j], acc[i][j], 0, 0, 0);
            }
        __syncthreads();  // next buffer staged (vmcnt drained), reads done
        cur ^= 1;
    }

#pragma unroll
    for (int j = 0; j < 4; ++j) {
        const int gcol = bcol * 128 + wn * 64 + j * 16 + (l & 15);
        const int tt = gcol >> 9;          // 0=q 1=k 2=v
        const int h  = (gcol >> 6) & 7;
        const int d  = gcol & 63;
        float* dst = (tt == 0) ? qf : (tt == 1) ? kf : v;
#pragma unroll
        for (int i = 0; i < 4; ++i)
#pragma unroll
            for (int r = 0; r < 4; ++r) {
                const int grow = brow * 128 + wm * 64 + i * 16 + (l >> 4) * 4 + r;
                const int b = grow >> 13, n = grow & 8191;
                float val = acc[i][j][r];
                if (tt < 2) val = elu1(val);
                dst[(((size_t)(b * HEADS + h) * NSEQ) + n) * HD + d] = val;
            }
    }
}

// ---------------------------------------------------------------------------
// GEMM 2 core (A pre-split in memory): 128x128 tile, BK=32, 4 waves.
// Waves stage {Ah, Al, Bh, Bl} via fragment-gather global_load_lds.
// ---------------------------------------------------------------------------
__device__ __forceinline__ void mfma3_core(const ushort* __restrict__ Ah,
                                           const ushort* __restrict__ Al,
                                           const ushort* __restrict__ BTh,
                                           const ushort* __restrict__ BTl,
                                           int brow, int bcol, char* lds,
                                           f32x4 acc[4][4]) {
    const int t = threadIdx.x;
    const int l = t & 63;
    const int w = t >> 6;        // staging role: 0:Ah 1:Al 2:Bh 3:Bl
    const int wm = w >> 1, wn = w & 1;

    const ushort* src = (w == 0) ? Ah : (w == 1) ? Al : (w == 2) ? BTh : BTl;
    const int rowbase = ((w < 2) ? brow : bcol) * 128;
    const ushort* gbase = src + (size_t)(rowbase + (l & 15)) * 512 + ((l >> 4) * 8);

    const f32x4 zero = {0.f, 0.f, 0.f, 0.f};
#pragma unroll
    for (int i = 0; i < 4; ++i)
#pragma unroll
        for (int j = 0; j < 4; ++j) acc[i][j] = zero;

    auto stage = [&](int buf, int kt) {
        const ushort* g = gbase + kt;
        char* ld = lds + buf * 32768 + w * 8192;
#pragma unroll
        for (int f = 0; f < 8; ++f)           // frag f covers rows f*16..f*16+15
            gload_lds16(g + (size_t)f * 16 * 512, ld + f * 1024);
    };

    stage(0, 0);
    __syncthreads();
    int cur = 0;
    for (int ks = 0; ks < 16; ++ks) {
        if (ks < 15) stage(cur ^ 1, (ks + 1) * 32);
        const char* Lb = lds + cur * 32768;
        bf16x8 ah[4], al[4], bh[4], bl[4];
#pragma unroll
        for (int i = 0; i < 4; ++i) {
            ah[i] = *(const bf16x8*)(Lb + 0 * 8192 + (wm * 4 + i) * 1024 + l * 16);
            al[i] = *(const bf16x8*)(Lb + 1 * 8192 + (wm * 4 + i) * 1024 + l * 16);
            bh[i] = *(const bf16x8*)(Lb + 2 * 8192 + (wn * 4 + i) * 1024 + l * 16);
            bl[i] = *(const bf16x8*)(Lb + 3 * 8192 + (wn * 4 + i) * 1024 + l * 16);
        }
#pragma unroll
        for (int i = 0; i < 4; ++i)
#pragma unroll
            for (int j = 0; j < 4; ++j) {
                acc[i][j] = __builtin_amdgcn_mfma_f32_16x16x32_bf16(ah[i], bh[j], acc[i][j], 0, 0, 0);
                acc[i][j] = __builtin_amdgcn_mfma_f32_16x16x32_bf16(ah[i], bl[j], acc[i][j], 0, 0, 0);
                acc[i][j] = __builtin_amdgcn_mfma_f32_16x16x32_bf16(al[i], bh[j], acc[i][j], 0, 0, 0);
            }
        __syncthreads();
        cur ^= 1;
    }
}

// ---------------------------------------------------------------------------
// GEMM 2: out = y @ w_proj + b_proj (M=65536, N=512, K=512).
// grid 2048 linear (XCD-swizzled), block 256.
// ---------------------------------------------------------------------------
__global__ __launch_bounds__(256, 2)
void proj_mfma_kernel(const ushort* __restrict__ Ah, const ushort* __restrict__ Al,
                      const ushort* __restrict__ BTh, const ushort* __restrict__ BTl,
                      const float* __restrict__ bp, float* __restrict__ out) {
    __shared__ __align__(16) char lds[65536];
    const int bid = blockIdx.x;
    const int swz = (bid & 7) * 256 + (bid >> 3);  // bijective: 2048 % 8 == 0
    const int brow = swz >> 2, bcol = swz & 3;
    f32x4 acc[4][4];
    mfma3_core(Ah, Al, BTh, BTl, brow, bcol, lds, acc);

    const int t = threadIdx.x, l = t & 63, w = t >> 6;
    const int wm = w >> 1, wn = w & 1;
#pragma unroll
    for (int j = 0; j < 4; ++j) {
        const int gcol = bcol * 128 + wn * 64 + j * 16 + (l & 15);
        const float bias = bp[gcol];
#pragma unroll
        for (int i = 0; i < 4; ++i)
#pragma unroll
            for (int r = 0; r < 4; ++r) {
                const int grow = brow * 128 + wm * 64 + i * 16 + (l >> 4) * 4 + r;
                out[(size_t)grow * CDIM + gcol] = acc[i][j][r] + bias;
            }
    }
}

// ---------------------------------------------------------------------------
// kv state partials: kv[d][e] = sum_n kf[n,d]*v[n,e]; ksum[d] = sum_n kf[n,d]
// grid (NSPLIT, 64), block 256
// ---------------------------------------------------------------------------
__global__ __launch_bounds__(256, 2)
void kv_state_kernel(const float* __restrict__ kf, const float* __restrict__ v,
                     float* __restrict__ kvpart, float* __restrict__ kspart) {
    __shared__ float kfs[8][64];
    __shared__ float vs[8][64];
    const int t  = threadIdx.x;
    const int s  = blockIdx.x;
    const int bh = blockIdx.y;
    const int d  = t >> 2;
    const int eg = (t & 3) << 4;
    const int ldr = t & 127;
    const int lrow = ldr >> 4;
    const int lseg = (ldr & 15) << 2;
    const float* src = (t < 128) ? (kf + (size_t)bh * NSEQ * HD)
                                 : (v  + (size_t)bh * NSEQ * HD);
    float acc[16];
#pragma unroll
    for (int j = 0; j < 16; j++) acc[j] = 0.f;
    float ks = 0.f;

    const int nbeg = s * (NSEQ / NSPLIT);
    for (int n = nbeg; n < nbeg + (NSEQ / NSPLIT); n += 8) {
        const float4 val = *(const float4*)&src[(size_t)(n + lrow) * HD + lseg];
        __syncthreads();
        if (t < 128) *(float4*)&kfs[lrow][lseg] = val;
        else         *(float4*)&vs[lrow][lseg]  = val;
        __syncthreads();
#pragma unroll
        for (int nn = 0; nn < 8; nn++) {
            const float kval = kfs[nn][d];
            ks += kval;
#pragma unroll
            for (int j = 0; j < 16; j++) acc[j] = fmaf(kval, vs[nn][eg + j], acc[j]);
        }
    }
    float* dst = kvpart + ((size_t)s * 64 + bh) * 4096 + d * 64 + eg;
#pragma unroll
    for (int u = 0; u < 4; u++)
        *(float4*)&dst[u * 4] = make_float4(acc[u*4+0], acc[u*4+1], acc[u*4+2], acc[u*4+3]);
    if ((t & 3) == 0) kspart[((size_t)s * 64 + bh) * 64 + d] = ks;
}

// ---------------------------------------------------------------------------
// reduce NSPLIT partials. grid(1040), block 256.
// ---------------------------------------------------------------------------
__global__ __launch_bounds__(256, 4)
void kv_reduce_kernel(const float* __restrict__ kvpart, const float* __restrict__ kspart,
                      float* __restrict__ kv, float* __restrict__ ksum) {
    const int idx = blockIdx.x * 256 + threadIdx.x;
    if (blockIdx.x < 1024) {
        float sum = 0.f;
#pragma unroll
        for (int u = 0; u < NSPLIT; u++) sum += kvpart[(size_t)u * 262144 + idx];
        kv[idx] = sum;
    } else {
        const int i2 = idx - 262144;
        float sum = 0.f;
#pragma unroll
        for (int u = 0; u < NSPLIT; u++) sum += kspart[(size_t)u * 4096 + i2];
        ksum[i2] = sum;
    }
}

// ---------------------------------------------------------------------------
// attn out: y[n,e] = (qf[n,:]@kv[:,e]) / (qf[n,:]@ksum + eps), written as
// bf16 hi/lo [B,N,C] for the proj GEMM.  grid (32, 64), block 256.
// ---------------------------------------------------------------------------
__global__ __launch_bounds__(256, 2)
void attn_out_kernel(const float* __restrict__ qf, const float* __restrict__ kv,
                     const float* __restrict__ ksum,
                     ushort* __restrict__ yh, ushort* __restrict__ yl) {
    __shared__ float kvl[64][64];
    __shared__ float qfl[64][68];
    __shared__ float ksl[64];
    const int t  = threadIdx.x;
    const int bh = blockIdx.y;
    const int n0 = blockIdx.x * 256;

    const float4* kvg = (const float4*)(kv + (size_t)bh * 4096);
#pragma unroll
    for (int u = 0; u < 4; u++) ((float4*)kvl)[t + u * 256] = kvg[t + u * 256];
    if (t < 64) ksl[t] = ksum[bh * 64 + t];

    const int nl = t >> 2;
    const int eg = (t & 3) << 4;
    const int b = bh >> 3, h = bh & 7;
    const float* qbase = qf + (size_t)bh * NSEQ * HD;

    for (int p = 0; p < 4; p++) {
        const int nb = n0 + p * 64;
        __syncthreads();
        const float4* qg = (const float4*)(qbase + (size_t)nb * HD);
#pragma unroll
        for (int u = 0; u < 4; u++) {
            const int f4 = t + u * 256;
            const int row = f4 >> 4, col = (f4 & 15) << 2;
            *(float4*)&qfl[row][col] = qg[f4];
        }
        __syncthreads();

        float z = 0.f;
#pragma unroll 8
        for (int d = 0; d < 64; ++d) z = fmaf(qfl[nl][d], ksl[d], z);

        float accv[16];
#pragma unroll
        for (int j = 0; j < 16; j++) accv[j] = 0.f;
#pragma unroll 4
        for (int d = 0; d < 64; ++d) {
            const float qv = qfl[nl][d];
#pragma unroll
            for (int j = 0; j < 16; j++) accv[j] = fmaf(qv, kvl[d][eg + j], accv[j]);
        }
        const float inv = 1.f / (z + 1e-6f);
        const size_t rowoff = ((size_t)b * NSEQ + (nb + nl)) * CDIM + h * 64 + eg;
#pragma unroll
        for (int u = 0; u < 4; u++) {
            ushort4 ho, lo4;
            const float o0 = accv[u*4+0]*inv, o1 = accv[u*4+1]*inv,
                        o2 = accv[u*4+2]*inv, o3 = accv[u*4+3]*inv;
            ho.x = f2bf_rne(o0); lo4.x = f2bf_rne(o0 - bf2f(ho.x));
            ho.y = f2bf_rne(o1); lo4.y = f2bf_rne(o1 - bf2f(ho.y));
            ho.z = f2bf_rne(o2); lo4.z = f2bf_rne(o2 - bf2f(ho.z));
            ho.w = f2bf_rne(o3); lo4.w = f2bf_rne(o3 - bf2f(ho.w));
            *(ushort4*)&yh[rowoff + u * 4] = ho;
            *(ushort4*)&yl[rowoff + u * 4] = lo4;
        }
    }
}

// ---------------------------------------------------------------------------
// Memory plan — ws PEAK 290,734,080 B ≈ 277.3 MiB (was 405 MiB; round-3 crash
// suspected ws_size OOB, so qf now lives in d_out, which is dead until proj).
//   d_out: qf [B,H,N,D] fp32 (128 MiB) -> overwritten by final out [B,N,C]
//   ws:
//   kf     @ 0           (134,217,728)  -- dead after kv_state; aliased by:
//       yh @ 0           ( 67,108,864)  [B,N,C] bf16 hi
//       yl @ 67,108,864  ( 67,108,864)  [B,N,C] bf16 lo
//   v      @ 134,217,728 (134,217,728)
//   wqh    @ 268,435,456 (  1,572,864)
//   wql    @ 270,008,320 (  1,572,864)
//   wph    @ 271,581,184 (    524,288)
//   wpl    @ 272,105,472 (    524,288)
//   kvpart @ 272,629,760 ( 16,777,216)
//   kspart @ 289,406,976 (    262,144)
//   kv     @ 289,669,120 (  1,048,576)
//   ksum   @ 290,717,696 (     16,384)
// Order: qkv(writes qf=d_out,kf,v) -> kv_state(reads kf,v) -> reduce ->
// attn_out(reads qf=d_out, writes yh/yl over dead kf) -> proj(reads yh/yl,
// writes d_out over dead qf).  No lifetime overlap.
// ---------------------------------------------------------------------------
extern "C" void kernel_launch(void* const* d_in, const int* in_sizes, int n_in,
                              void* d_out, int out_size, void* d_ws, size_t ws_size,
                              hipStream_t stream) {
    const float* x      = (const float*)d_in[0];
    const float* w_qkv  = (const float*)d_in[1];
    const float* w_proj = (const float*)d_in[2];
    const float* b_proj = (const float*)d_in[3];
    float* out = (float*)d_out;
    char* W = (char*)d_ws;

    float*  qf    = out;                            // d_out as scratch until proj
    float*  kf    = (float*)(W);
    ushort* yh    = (ushort*)(W);                   // alias kf (dead after kv_state)
    ushort* yl    = (ushort*)(W + 67108864ull);
    float*  vv    = (float*)(W + 134217728ull);
    ushort* wqh   = (ushort*)(W + 268435456ull);
    ushort* wql   = (ushort*)(W + 270008320ull);
    ushort* wph   = (ushort*)(W + 271581184ull);
    ushort* wpl   = (ushort*)(W + 272105472ull);
    float* kvpart = (float*)(W + 272629760ull);
    float* kspart = (float*)(W + 289406976ull);
    float* kv     = (float*)(W + 289669120ull);
    float* ksum   = (float*)(W + 290717696ull);

    split_wT_kernel<<<dim3(48, 16), 256, 0, stream>>>(w_qkv, wqh, wql, 1536);
    split_wT_kernel<<<dim3(16, 16), 256, 0, stream>>>(w_proj, wph, wpl, 512);
    qkv_mfma_kernel<<<6144, 256, 0, stream>>>(x, wqh, wql, qf, kf, vv);
    kv_state_kernel<<<dim3(NSPLIT, 64), 256, 0, stream>>>(kf, vv, kvpart, kspart);
    kv_reduce_kernel<<<1040, 256, 0, stream>>>(kvpart, kspart, kv, ksum);
    attn_out_kernel<<<dim3(32, 64), 256, 0, stream>>>(qf, kv, ksum, yh, yl);
    proj_mfma_kernel<<<2048, 256, 0, stream>>>(yh, yl, wph, wpl, b_proj, out);

    (void)in_sizes; (void)n_in; (void)out_size; (void)ws_size;
}

// Round 7
// 1002.002 us; speedup vs baseline: 1.1045x; 1.1045x over previous
//
#include <hip/hip_runtime.h>
#include <cstdint>
#include <cstddef>

// Problem constants (fixed by reference)
#define BDIM 8
#define NSEQ 8192
#define CDIM 512
#define HEADS 8
#define HD 64
#define NSPLIT 16

typedef short bf16x8 __attribute__((ext_vector_type(8)));
typedef float f32x4 __attribute__((ext_vector_type(4)));

typedef const __attribute__((address_space(1))) void* gas_cvp;
typedef __attribute__((address_space(3))) void* las_vp;

// Async 16B global->LDS. LDS dest is wave-uniform base + lane*16 (HW adds it).
__device__ __forceinline__ void gload_lds16(const void* g, void* l) {
    __builtin_amdgcn_global_load_lds((gas_cvp)g, (las_vp)l, 16, 0, 0);
}

// bf16 helpers
__device__ __forceinline__ ushort f2bf_rne(float f) {
    uint32_t u = __float_as_uint(f);
    u += 0x7FFFu + ((u >> 16) & 1u);
    return (ushort)(u >> 16);
}
__device__ __forceinline__ float bf2f(ushort h) {
    return __uint_as_float(((uint32_t)h) << 16);
}

// elu(x)+1 with alpha=1:  x>0 ? x+1 : exp(x)
__device__ __forceinline__ float elu1(float x) {
    return x > 0.f ? x + 1.f : __expf(x);
}

// ---------------------------------------------------------------------------
// Pre-pass A: split x [65536*512] f32 -> x_hi,x_lo bf16 (same layout, RNE).
// Removes the in-loop fp32 A-loads + split VALU from the qkv GEMM (round-6
// PMC: latency-bound, MfmaUtil 19.7%, nothing saturated).
// ---------------------------------------------------------------------------
__global__ __launch_bounds__(256)
void split_x_kernel(const float4* __restrict__ x, ushort4* __restrict__ xh,
                    ushort4* __restrict__ xl, int n4) {
    for (int i = blockIdx.x * 256 + threadIdx.x; i < n4; i += gridDim.x * 256) {
        const float4 v = x[i];
        ushort4 h, l;
        h.x = f2bf_rne(v.x); l.x = f2bf_rne(v.x - bf2f(h.x));
        h.y = f2bf_rne(v.y); l.y = f2bf_rne(v.y - bf2f(h.y));
        h.z = f2bf_rne(v.z); l.z = f2bf_rne(v.z - bf2f(h.z));
        h.w = f2bf_rne(v.w); l.w = f2bf_rne(v.w - bf2f(h.w));
        xh[i] = h; xl[i] = l;
    }
}

// ---------------------------------------------------------------------------
// Pre-pass B: W [512][N] f32 -> WT_hi/WT_lo [N][512] bf16 (transpose + split, RNE)
// grid (N/32, 16), block 256 (32x8)
// ---------------------------------------------------------------------------
__global__ __launch_bounds__(256)
void split_wT_kernel(const float* __restrict__ W, ushort* __restrict__ WTh,
                     ushort* __restrict__ WTl, int N) {
    __shared__ float tile[32][33];
    const int tx = threadIdx.x & 31, ty = threadIdx.x >> 5;
    const int bx = blockIdx.x, by = blockIdx.y;
#pragma unroll
    for (int r = 0; r < 4; ++r)
        tile[ty + 8 * r][tx] = W[(size_t)(by * 32 + ty + 8 * r) * N + bx * 32 + tx];
    __syncthreads();
#pragma unroll
    for (int r = 0; r < 4; ++r) {
        const int n = bx * 32 + ty + 8 * r;   // output row (N-dim)
        const int k = by * 32 + tx;           // output col (K-dim)
        const float v = tile[tx][ty + 8 * r]; // = W[k][n]
        const ushort h = f2bf_rne(v);
        WTh[(size_t)n * 512 + k] = h;
        WTl[(size_t)n * 512 + k] = f2bf_rne(v - bf2f(h));
    }
}

// ---------------------------------------------------------------------------
// bf16x3 MFMA GEMM core (all operands pre-split in memory): 128x128 tile,
// BK=32, 4 waves.  Waves stage {Ah, Al, Bh, Bl} via fragment-gather
// global_load_lds; LDS is fragment-linear (zero bank conflicts, verified r6).
// This exact core ran correctly as proj_mfma in round 6.
// mfma_f32_16x16x32_bf16 lane layouts: A row=l&15, k=(l>>4)*8+e; B col=l&15,
// k=(l>>4)*8+e; D col=l&15, row=(l>>4)*4+reg.
// ---------------------------------------------------------------------------
__device__ __forceinline__ void mfma3_core(const ushort* __restrict__ Ah,
                                           const ushort* __restrict__ Al,
                                           const ushort* __restrict__ BTh,
                                           const ushort* __restrict__ BTl,
                                           int brow, int bcol, char* lds,
                                           f32x4 acc[4][4]) {
    const int t = threadIdx.x;
    const int l = t & 63;
    const int w = t >> 6;        // staging role: 0:Ah 1:Al 2:Bh 3:Bl
    const int wm = w >> 1, wn = w & 1;

    const ushort* src = (w == 0) ? Ah : (w == 1) ? Al : (w == 2) ? BTh : BTl;
    const int rowbase = ((w < 2) ? brow : bcol) * 128;
    const ushort* gbase = src + (size_t)(rowbase + (l & 15)) * 512 + ((l >> 4) * 8);

    const f32x4 zero = {0.f, 0.f, 0.f, 0.f};
#pragma unroll
    for (int i = 0; i < 4; ++i)
#pragma unroll
        for (int j = 0; j < 4; ++j) acc[i][j] = zero;

    auto stage = [&](int buf, int kt) {
        const ushort* g = gbase + kt;
        char* ld = lds + buf * 32768 + w * 8192;
#pragma unroll
        for (int f = 0; f < 8; ++f)           // frag f covers rows f*16..f*16+15
            gload_lds16(g + (size_t)f * 16 * 512, ld + f * 1024);
    };

    stage(0, 0);
    __syncthreads();
    int cur = 0;
    for (int ks = 0; ks < 16; ++ks) {
        if (ks < 15) stage(cur ^ 1, (ks + 1) * 32);
        const char* Lb = lds + cur * 32768;
        bf16x8 ah[4], al[4], bh[4], bl[4];
#pragma unroll
        for (int i = 0; i < 4; ++i) {
            ah[i] = *(const bf16x8*)(Lb + 0 * 8192 + (wm * 4 + i) * 1024 + l * 16);
            al[i] = *(const bf16x8*)(Lb + 1 * 8192 + (wm * 4 + i) * 1024 + l * 16);
            bh[i] = *(const bf16x8*)(Lb + 2 * 8192 + (wn * 4 + i) * 1024 + l * 16);
            bl[i] = *(const bf16x8*)(Lb + 3 * 8192 + (wn * 4 + i) * 1024 + l * 16);
        }
#pragma unroll
        for (int i = 0; i < 4; ++i)
#pragma unroll
            for (int j = 0; j < 4; ++j) {
                acc[i][j] = __builtin_amdgcn_mfma_f32_16x16x32_bf16(ah[i], bh[j], acc[i][j], 0, 0, 0);
                acc[i][j] = __builtin_amdgcn_mfma_f32_16x16x32_bf16(ah[i], bl[j], acc[i][j], 0, 0, 0);
                acc[i][j] = __builtin_amdgcn_mfma_f32_16x16x32_bf16(al[i], bh[j], acc[i][j], 0, 0, 0);
            }
        __syncthreads();
        cur ^= 1;
    }
}

// ---------------------------------------------------------------------------
// GEMM 1: qkv = x @ w_qkv (M=65536, N=1536, K=512), A pre-split (xh/xl).
// Epilogue: elu+1 on q,k; scatter to qf/kf/v [B,H,N,D] fp32.
// grid 6144 linear (XCD-swizzled), block 256.
// ---------------------------------------------------------------------------
__global__ __launch_bounds__(256, 2)
void qkv_mfma_kernel(const ushort* __restrict__ Ah, const ushort* __restrict__ Al,
                     const ushort* __restrict__ BTh, const ushort* __restrict__ BTl,
                     float* __restrict__ qf, float* __restrict__ kf, float* __restrict__ v) {
    __shared__ __align__(16) char lds[65536];
    const int bid = blockIdx.x;
    const int swz = (bid & 7) * 768 + (bid >> 3);  // bijective: 6144 % 8 == 0
    const int brow = swz / 12, bcol = swz % 12;
    f32x4 acc[4][4];
    mfma3_core(Ah, Al, BTh, BTl, brow, bcol, lds, acc);

    const int t = threadIdx.x, l = t & 63, w = t >> 6;
    const int wm = w >> 1, wn = w & 1;
#pragma unroll
    for (int j = 0; j < 4; ++j) {
        const int gcol = bcol * 128 + wn * 64 + j * 16 + (l & 15);
        const int tt = gcol >> 9;          // 0=q 1=k 2=v
        const int h  = (gcol >> 6) & 7;
        const int d  = gcol & 63;
        float* dst = (tt == 0) ? qf : (tt == 1) ? kf : v;
#pragma unroll
        for (int i = 0; i < 4; ++i)
#pragma unroll
            for (int r = 0; r < 4; ++r) {
                const int grow = brow * 128 + wm * 64 + i * 16 + (l >> 4) * 4 + r;
                const int b = grow >> 13, n = grow & 8191;
                float val = acc[i][j][r];
                if (tt < 2) val = elu1(val);
                dst[(((size_t)(b * HEADS + h) * NSEQ) + n) * HD + d] = val;
            }
    }
}

// ---------------------------------------------------------------------------
// GEMM 2: out = y @ w_proj + b_proj (M=65536, N=512, K=512).
// grid 2048 linear (XCD-swizzled), block 256.
// ---------------------------------------------------------------------------
__global__ __launch_bounds__(256, 2)
void proj_mfma_kernel(const ushort* __restrict__ Ah, const ushort* __restrict__ Al,
                      const ushort* __restrict__ BTh, const ushort* __restrict__ BTl,
                      const float* __restrict__ bp, float* __restrict__ out) {
    __shared__ __align__(16) char lds[65536];
    const int bid = blockIdx.x;
    const int swz = (bid & 7) * 256 + (bid >> 3);  // bijective: 2048 % 8 == 0
    const int brow = swz >> 2, bcol = swz & 3;
    f32x4 acc[4][4];
    mfma3_core(Ah, Al, BTh, BTl, brow, bcol, lds, acc);

    const int t = threadIdx.x, l = t & 63, w = t >> 6;
    const int wm = w >> 1, wn = w & 1;
#pragma unroll
    for (int j = 0; j < 4; ++j) {
        const int gcol = bcol * 128 + wn * 64 + j * 16 + (l & 15);
        const float bias = bp[gcol];
#pragma unroll
        for (int i = 0; i < 4; ++i)
#pragma unroll
            for (int r = 0; r < 4; ++r) {
                const int grow = brow * 128 + wm * 64 + i * 16 + (l >> 4) * 4 + r;
                out[(size_t)grow * CDIM + gcol] = acc[i][j][r] + bias;
            }
    }
}

// ---------------------------------------------------------------------------
// kv state partials: kv[d][e] = sum_n kf[n,d]*v[n,e]; ksum[d] = sum_n kf[n,d]
// grid (NSPLIT, 64), block 256
// ---------------------------------------------------------------------------
__global__ __launch_bounds__(256, 2)
void kv_state_kernel(const float* __restrict__ kf, const float* __restrict__ v,
                     float* __restrict__ kvpart, float* __restrict__ kspart) {
    __shared__ float kfs[8][64];
    __shared__ float vs[8][64];
    const int t  = threadIdx.x;
    const int s  = blockIdx.x;
    const int bh = blockIdx.y;
    const int d  = t >> 2;
    const int eg = (t & 3) << 4;
    const int ldr = t & 127;
    const int lrow = ldr >> 4;
    const int lseg = (ldr & 15) << 2;
    const float* src = (t < 128) ? (kf + (size_t)bh * NSEQ * HD)
                                 : (v  + (size_t)bh * NSEQ * HD);
    float acc[16];
#pragma unroll
    for (int j = 0; j < 16; j++) acc[j] = 0.f;
    float ks = 0.f;

    const int nbeg = s * (NSEQ / NSPLIT);
    for (int n = nbeg; n < nbeg + (NSEQ / NSPLIT); n += 8) {
        const float4 val = *(const float4*)&src[(size_t)(n + lrow) * HD + lseg];
        __syncthreads();
        if (t < 128) *(float4*)&kfs[lrow][lseg] = val;
        else         *(float4*)&vs[lrow][lseg]  = val;
        __syncthreads();
#pragma unroll
        for (int nn = 0; nn < 8; nn++) {
            const float kval = kfs[nn][d];
            ks += kval;
#pragma unroll
            for (int j = 0; j < 16; j++) acc[j] = fmaf(kval, vs[nn][eg + j], acc[j]);
        }
    }
    float* dst = kvpart + ((size_t)s * 64 + bh) * 4096 + d * 64 + eg;
#pragma unroll
    for (int u = 0; u < 4; u++)
        *(float4*)&dst[u * 4] = make_float4(acc[u*4+0], acc[u*4+1], acc[u*4+2], acc[u*4+3]);
    if ((t & 3) == 0) kspart[((size_t)s * 64 + bh) * 64 + d] = ks;
}

// ---------------------------------------------------------------------------
// reduce NSPLIT partials. grid(1040), block 256.
// ---------------------------------------------------------------------------
__global__ __launch_bounds__(256, 4)
void kv_reduce_kernel(const float* __restrict__ kvpart, const float* __restrict__ kspart,
                      float* __restrict__ kv, float* __restrict__ ksum) {
    const int idx = blockIdx.x * 256 + threadIdx.x;
    if (blockIdx.x < 1024) {
        float sum = 0.f;
#pragma unroll
        for (int u = 0; u < NSPLIT; u++) sum += kvpart[(size_t)u * 262144 + idx];
        kv[idx] = sum;
    } else {
        const int i2 = idx - 262144;
        float sum = 0.f;
#pragma unroll
        for (int u = 0; u < NSPLIT; u++) sum += kspart[(size_t)u * 4096 + i2];
        ksum[i2] = sum;
    }
}

// ---------------------------------------------------------------------------
// attn out: y[n,e] = (qf[n,:]@kv[:,e]) / (qf[n,:]@ksum + eps), written as
// bf16 hi/lo [B,N,C] for the proj GEMM.  grid (32, 64), block 256.
// ---------------------------------------------------------------------------
__global__ __launch_bounds__(256, 2)
void attn_out_kernel(const float* __restrict__ qf, const float* __restrict__ kv,
                     const float* __restrict__ ksum,
                     ushort* __restrict__ yh, ushort* __restrict__ yl) {
    __shared__ float kvl[64][64];
    __shared__ float qfl[64][68];
    __shared__ float ksl[64];
    const int t  = threadIdx.x;
    const int bh = blockIdx.y;
    const int n0 = blockIdx.x * 256;

    const float4* kvg = (const float4*)(kv + (size_t)bh * 4096);
#pragma unroll
    for (int u = 0; u < 4; u++) ((float4*)kvl)[t + u * 256] = kvg[t + u * 256];
    if (t < 64) ksl[t] = ksum[bh * 64 + t];

    const int nl = t >> 2;
    const int eg = (t & 3) << 4;
    const int b = bh >> 3, h = bh & 7;
    const float* qbase = qf + (size_t)bh * NSEQ * HD;

    for (int p = 0; p < 4; p++) {
        const int nb = n0 + p * 64;
        __syncthreads();
        const float4* qg = (const float4*)(qbase + (size_t)nb * HD);
#pragma unroll
        for (int u = 0; u < 4; u++) {
            const int f4 = t + u * 256;
            const int row = f4 >> 4, col = (f4 & 15) << 2;
            *(float4*)&qfl[row][col] = qg[f4];
        }
        __syncthreads();

        float z = 0.f;
#pragma unroll 8
        for (int d = 0; d < 64; ++d) z = fmaf(qfl[nl][d], ksl[d], z);

        float accv[16];
#pragma unroll
        for (int j = 0; j < 16; j++) accv[j] = 0.f;
#pragma unroll 4
        for (int d = 0; d < 64; ++d) {
            const float qv = qfl[nl][d];
#pragma unroll
            for (int j = 0; j < 16; j++) accv[j] = fmaf(qv, kvl[d][eg + j], accv[j]);
        }
        const float inv = 1.f / (z + 1e-6f);
        const size_t rowoff = ((size_t)b * NSEQ + (nb + nl)) * CDIM + h * 64 + eg;
#pragma unroll
        for (int u = 0; u < 4; u++) {
            ushort4 ho, lo4;
            const float o0 = accv[u*4+0]*inv, o1 = accv[u*4+1]*inv,
                        o2 = accv[u*4+2]*inv, o3 = accv[u*4+3]*inv;
            ho.x = f2bf_rne(o0); lo4.x = f2bf_rne(o0 - bf2f(ho.x));
            ho.y = f2bf_rne(o1); lo4.y = f2bf_rne(o1 - bf2f(ho.y));
            ho.z = f2bf_rne(o2); lo4.z = f2bf_rne(o2 - bf2f(ho.z));
            ho.w = f2bf_rne(o3); lo4.w = f2bf_rne(o3 - bf2f(ho.w));
            *(ushort4*)&yh[rowoff + u * 4] = ho;
            *(ushort4*)&yl[rowoff + u * 4] = lo4;
        }
    }
}

// ---------------------------------------------------------------------------
// Memory plan — ws PEAK 406,847,488 B ≈ 388.0 MiB (round-6 PASSED at 277 MiB
// => ws_size >= 277 MiB; round-3 crash at 533 MiB => likely ws_size = 512 MiB).
//   d_out: qf [B,H,N,D] fp32 (128 MiB) -> overwritten by final out [B,N,C]
//   ws:
//   xh     @ 0           ( 67,108,864)  bf16 hi of x -- dead after qkv; aliased:
//       kvpart @ 0           (16,777,216)
//       kspart @ 16,777,216  (   262,144)
//       kv     @ 17,039,360  ( 1,048,576)
//       ksum   @ 18,087,936  (    16,384)
//   xl     @ 67,108,864  ( 67,108,864)  bf16 lo of x
//   kf     @ 134,217,728 (134,217,728)  -- dead after kv_state; aliased:
//       yh @ 134,217,728 ( 67,108,864)  [B,N,C] bf16 hi
//       yl @ 201,326,592 ( 67,108,864)  [B,N,C] bf16 lo
//   v      @ 268,435,456 (134,217,728)
//   wqh    @ 402,653,184 (  1,572,864)
//   wql    @ 404,226,048 (  1,572,864)
//   wph    @ 405,798,912 (    524,288)
//   wpl    @ 406,323,200 (    524,288)
// Order: split_x(w xh,xl) -> split_wT(w w*) -> qkv(r xh,xl,wq; w qf,kf,v) ->
// kv_state(r kf,v; w kvpart/kspart over dead xh) -> reduce -> attn_out(r qf;
// w yh/yl over dead kf) -> proj(r yh/yl,wp; w d_out over dead qf).
// ---------------------------------------------------------------------------
extern "C" void kernel_launch(void* const* d_in, const int* in_sizes, int n_in,
                              void* d_out, int out_size, void* d_ws, size_t ws_size,
                              hipStream_t stream) {
    const float* x      = (const float*)d_in[0];
    const float* w_qkv  = (const float*)d_in[1];
    const float* w_proj = (const float*)d_in[2];
    const float* b_proj = (const float*)d_in[3];
    float* out = (float*)d_out;
    char* W = (char*)d_ws;

    float*  qf    = out;                            // d_out as scratch until proj
    ushort* xh    = (ushort*)(W);
    float*  kvpart= (float*)(W);                    // alias xh (dead after qkv)
    float*  kspart= (float*)(W + 16777216ull);
    float*  kv    = (float*)(W + 17039360ull);
    float*  ksum  = (float*)(W + 18087936ull);
    ushort* xl    = (ushort*)(W + 67108864ull);
    float*  kf    = (float*)(W + 134217728ull);
    ushort* yh    = (ushort*)(W + 134217728ull);    // alias kf (dead after kv_state)
    ushort* yl    = (ushort*)(W + 201326592ull);
    float*  vv    = (float*)(W + 268435456ull);
    ushort* wqh   = (ushort*)(W + 402653184ull);
    ushort* wql   = (ushort*)(W + 404226048ull);
    ushort* wph   = (ushort*)(W + 405798912ull);
    ushort* wpl   = (ushort*)(W + 406323200ull);

    split_x_kernel<<<2048, 256, 0, stream>>>((const float4*)x, (ushort4*)xh,
                                             (ushort4*)xl, 8388608);
    split_wT_kernel<<<dim3(48, 16), 256, 0, stream>>>(w_qkv, wqh, wql, 1536);
    split_wT_kernel<<<dim3(16, 16), 256, 0, stream>>>(w_proj, wph, wpl, 512);
    qkv_mfma_kernel<<<6144, 256, 0, stream>>>(xh, xl, wqh, wql, qf, kf, vv);
    kv_state_kernel<<<dim3(NSPLIT, 64), 256, 0, stream>>>(kf, vv, kvpart, kspart);
    kv_reduce_kernel<<<1040, 256, 0, stream>>>(kvpart, kspart, kv, ksum);
    attn_out_kernel<<<dim3(32, 64), 256, 0, stream>>>(qf, kv, ksum, yh, yl);
    proj_mfma_kernel<<<2048, 256, 0, stream>>>(yh, yl, wph, wpl, b_proj, out);

    (void)in_sizes; (void)n_in; (void)out_size; (void)ws_size;
}